// Round 12
// baseline (390.952 us; speedup 1.0000x reference)
//
#include <hip/hip_runtime.h>

#define N_NODES 50000
#define N_EDGES 600000
#define DFEAT   128
#define SCAN_NB 196                      // 196 blocks of 256 counts (>= 50000/256)

typedef __attribute__((ext_vector_type(8))) short short8;
typedef __attribute__((ext_vector_type(4))) float floatx4;

__device__ __forceinline__ unsigned short f2bf_rtne(float f) {
    unsigned b = __float_as_uint(f);
    return (unsigned short)((b + 0x7FFFu + ((b >> 16) & 1u)) >> 16);
}
__device__ __forceinline__ float bf2f(unsigned short u) {
    return __uint_as_float(((unsigned)u) << 16);
}

// ================= prep: zero cnt/ctrs | x->bf16 table | W split/swizzle =========
__global__ __launch_bounds__(256) void sage_prep_kernel(
        const float* __restrict__ x,
        const float* __restrict__ Ws0, const float* __restrict__ Wn0,
        const float* __restrict__ Ws1, const float* __restrict__ Wn1,
        const float* __restrict__ Ws2, const float* __restrict__ Wn2,
        unsigned short* __restrict__ Whi0, unsigned short* __restrict__ Wlo0,
        unsigned short* __restrict__ Whi1, unsigned short* __restrict__ Wlo1,
        unsigned short* __restrict__ Whi2, unsigned short* __restrict__ Wlo2,
        unsigned short* __restrict__ hb, int* __restrict__ cnt,
        unsigned* __restrict__ ctrs)
{
    const int gtid = blockIdx.x * 256 + threadIdx.x;
    const int gsz  = gridDim.x * 256;
    if (gtid < 8) ctrs[gtid] = 0u;
    for (int i = gtid; i < 50176; i += gsz) cnt[i] = 0;
    for (int i = gtid; i < N_NODES * DFEAT / 4; i += gsz) {
        float4 v = ((const float4*)x)[i];
        ushort4 o;
        o.x = f2bf_rtne(v.x); o.y = f2bf_rtne(v.y);
        o.z = f2bf_rtne(v.z); o.w = f2bf_rtne(v.w);
        ((ushort4*)hb)[i] = o;
    }
    for (int it = gtid; it < 160 * 64; it += gsz) {
        int fid_g = it >> 6;
        int lane  = it & 63;
        const float *Ws, *Wn;
        unsigned short *Whi, *Wlo;
        int N, fid;
        if (fid_g < 64)       { Ws = Ws0; Wn = Wn0; Whi = Whi0; Wlo = Wlo0; N = 128; fid = fid_g; }
        else if (fid_g < 128) { Ws = Ws1; Wn = Wn1; Whi = Whi1; Wlo = Wlo1; N = 128; fid = fid_g - 64; }
        else                  { Ws = Ws2; Wn = Wn2; Whi = Whi2; Wlo = Wlo2; N = 64;  fid = fid_g - 128; }
        int NT = N / 16;
        int kt = fid / NT, nt = fid % NT;
        int kbase = kt * 32 + (lane >> 4) * 8;
        int n = nt * 16 + (lane & 15);
        long base = ((long)fid * 64 + lane) * 8;
        #pragma unroll
        for (int j = 0; j < 8; j++) {
            int k = kbase + j;
            float w = (k < 128) ? Ws[k * N + n] : Wn[(k - 128) * N + n];
            unsigned bb = __float_as_uint(w);
            unsigned hib = bb & 0xFFFF0000u;
            float lo = w - __uint_as_float(hib);
            Whi[base + j] = (unsigned short)(bb >> 16);
            Wlo[base + j] = (unsigned short)(__float_as_uint(lo) >> 16);
        }
    }
}

// ================= software barrier for co-resident 196-block grid =============
__device__ __forceinline__ void csr_barrier(unsigned* ctr, unsigned* flag, int nb) {
    __syncthreads();
    if (threadIdx.x == 0) {
        __threadfence();
        unsigned old = __hip_atomic_fetch_add(ctr, 1u, __ATOMIC_ACQ_REL,
                                              __HIP_MEMORY_SCOPE_AGENT);
        if (old == (unsigned)(nb - 1)) {
            __hip_atomic_store(flag, 1u, __ATOMIC_RELEASE, __HIP_MEMORY_SCOPE_AGENT);
        } else {
            while (__hip_atomic_load(flag, __ATOMIC_ACQUIRE,
                                     __HIP_MEMORY_SCOPE_AGENT) == 0u)
                __builtin_amdgcn_s_sleep(2);
        }
        __threadfence();
    }
    __syncthreads();
}

// ================= CSR build: hist + bsum/ticket-scan + scan2 + fill ===========
// EXACTLY 196 blocks x 256 threads — all co-resident (784 wave-slots of 8192),
// so the software barriers cannot deadlock.
__global__ __launch_bounds__(256) void sage_csr_kernel(
        const int* __restrict__ src, const int* __restrict__ dst,
        int* __restrict__ cnt, int* __restrict__ bsum,
        int* __restrict__ row_ptr, int* __restrict__ cursor,
        float* __restrict__ invdeg, unsigned short* __restrict__ sorted_src,
        unsigned* __restrict__ ctrs)
{
    const int t = threadIdx.x;
    const int b = blockIdx.x;
    const int gtid = b * 256 + t;
    const int gsz  = SCAN_NB * 256;

    // ---- phase 0: histogram (cnt zeroed by prep) ----
    for (int e = gtid; e < N_EDGES; e += gsz) atomicAdd(&cnt[dst[e]], 1);
    csr_barrier(&ctrs[0], &ctrs[1], SCAN_NB);

    // ---- phase 1: per-tile sums + last-arriving-block exclusive scan ----
    __shared__ int ws4[4];
    __shared__ int lastflag;
    int i = b * 256 + t;
    int v = (i < N_NODES) ? cnt[i] : 0;
    {
        int r = v;
        #pragma unroll
        for (int off = 32; off > 0; off >>= 1) r += __shfl_down(r, off);
        if ((t & 63) == 0) ws4[t >> 6] = r;
        __syncthreads();
        if (t == 0) {
            bsum[b] = ws4[0] + ws4[1] + ws4[2] + ws4[3];
            __threadfence();
            unsigned old = __hip_atomic_fetch_add(&ctrs[2], 1u, __ATOMIC_ACQ_REL,
                                                  __HIP_MEMORY_SCOPE_AGENT);
            lastflag = (old == (unsigned)(SCAN_NB - 1)) ? 1 : 0;
        }
        __syncthreads();
        if (lastflag) {
            int v2 = (t < SCAN_NB) ? bsum[t] : 0;
            int lane = t & 63, wid = t >> 6;
            int incl = v2;
            #pragma unroll
            for (int off = 1; off < 64; off <<= 1) {
                int y = __shfl_up(incl, off);
                if (lane >= off) incl += y;
            }
            __shared__ int sw2[4];
            if (lane == 63) sw2[wid] = incl;
            __syncthreads();
            int wpre = 0;
            for (int w = 0; w < wid; w++) wpre += sw2[w];
            if (t < SCAN_NB) bsum[t] = wpre + incl - v2;   // exclusive
            __syncthreads();
            if (t == 0) {
                __threadfence();
                __hip_atomic_store(&ctrs[3], 1u, __ATOMIC_RELEASE,
                                   __HIP_MEMORY_SCOPE_AGENT);
            }
        } else {
            if (t == 0) {
                while (__hip_atomic_load(&ctrs[3], __ATOMIC_ACQUIRE,
                                         __HIP_MEMORY_SCOPE_AGENT) == 0u)
                    __builtin_amdgcn_s_sleep(2);
                __threadfence();
            }
        }
        __syncthreads();
    }

    // ---- phase 2: local scan + offset -> row_ptr / cursor / invdeg ----
    {
        int lane = t & 63, wid = t >> 6;
        int incl = v;
        #pragma unroll
        for (int off = 1; off < 64; off <<= 1) {
            int y = __shfl_up(incl, off);
            if (lane >= off) incl += y;
        }
        __shared__ int sws[4];
        if (lane == 63) sws[wid] = incl;
        __syncthreads();
        int wpre = 0;
        for (int w = 0; w < wid; w++) wpre += sws[w];
        int excl = bsum[b] + wpre + incl - v;
        if (i < N_NODES) {
            row_ptr[i] = excl;
            cursor[i]  = excl;
            invdeg[i]  = 1.0f / fmaxf((float)v, 1.0f);
        }
        if (i == N_NODES - 1) row_ptr[N_NODES] = excl + v;
    }
    csr_barrier(&ctrs[4], &ctrs[5], SCAN_NB);

    // ---- phase 3: fill sorted_src via cursor ----
    for (int e = gtid; e < N_EDGES; e += gsz) {
        int p = atomicAdd(&cursor[dst[e]], 1);
        sorted_src[p] = (unsigned short)src[e];
    }
}

// ================= fused gather + all-bf16 MFMA layer kernel =================
// 1024 threads = 16 waves = 32 nodes/block (wave gathers nodes w and w+16 —
// only 2-serial, preserving latency-hiding parallelism; r10's 8-serial failed).
// Gather body identical to r11's standalone kernel (bit-identical sums), mean
// written bf16 to LDS. Then:
//   N=128: wave w -> row-tile (w&1), col-tile (w>>1); full K; 16 MFMAs.
//   N=64 : wave pairs K-split (self vs mean) + LDS reduce.
template<int NT, bool RELU, bool FINAL>
__global__ __launch_bounds__(1024) void sage_layer_kernel(
        const unsigned short* __restrict__ hb_in,
        const int* __restrict__ row_ptr, const unsigned short* __restrict__ sorted_src,
        const float* __restrict__ invdeg,
        const unsigned short* __restrict__ Whi, const unsigned short* __restrict__ Wlo,
        const float* __restrict__ bias, float* __restrict__ out,
        unsigned short* __restrict__ hb_out, int M)
{
    constexpr int N   = NT * 16;
    constexpr int LDM = 136;   // ushorts; row stride 272B: 16B-aligned b128 reads

    __shared__ unsigned short mean_s[32 * LDM];
    __shared__ float red_s[(NT == 4) ? 8 * 64 * 4 : 4];

    const int t    = threadIdx.x;
    const int w    = t >> 6;
    const int lane = t & 63;
    const int base = blockIdx.x * 32;

    // ---- phase 1: gather (r11 paired-edge wave-per-node form) ----
    const int half = lane >> 5;
    const int fq   = lane & 31;
    #pragma unroll 1
    for (int rep = 0; rep < 2; rep++) {
        const int nl = w + rep * 16;
        const int node = base + nl;
        if (node < M) {
            const int beg = row_ptr[node];
            const int end = row_ptr[node + 1];
            float4 s0 = make_float4(0.f, 0.f, 0.f, 0.f);
            float4 s1 = make_float4(0.f, 0.f, 0.f, 0.f);
            int e = beg + half;
            for (; e + 2 < end; e += 4) {
                int sA = sorted_src[e];
                int sB = sorted_src[e + 2];
                ushort4 vA = *(const ushort4*)(hb_in + (long)sA * DFEAT + fq * 4);
                ushort4 vB = *(const ushort4*)(hb_in + (long)sB * DFEAT + fq * 4);
                s0.x += bf2f(vA.x); s0.y += bf2f(vA.y); s0.z += bf2f(vA.z); s0.w += bf2f(vA.w);
                s1.x += bf2f(vB.x); s1.y += bf2f(vB.y); s1.z += bf2f(vB.z); s1.w += bf2f(vB.w);
            }
            for (; e < end; e += 2) {
                int sA = sorted_src[e];
                ushort4 vA = *(const ushort4*)(hb_in + (long)sA * DFEAT + fq * 4);
                s0.x += bf2f(vA.x); s0.y += bf2f(vA.y); s0.z += bf2f(vA.z); s0.w += bf2f(vA.w);
            }
            float sx = s0.x + s1.x, sy = s0.y + s1.y, sz = s0.z + s1.z, sw = s0.w + s1.w;
            sx += __shfl_down(sx, 32);
            sy += __shfl_down(sy, 32);
            sz += __shfl_down(sz, 32);
            sw += __shfl_down(sw, 32);
            if (half == 0) {
                float sc = invdeg[node];
                ushort4 r4;
                r4.x = f2bf_rtne(sx * sc); r4.y = f2bf_rtne(sy * sc);
                r4.z = f2bf_rtne(sz * sc); r4.w = f2bf_rtne(sw * sc);
                *(ushort4*)&mean_s[nl * LDM + fq * 4] = r4;
            }
        }
    }
    __syncthreads();

    // ---- phase 2: MFMA ----
    const int q = lane >> 4, l16 = lane & 15;

    if constexpr (NT == 8) {
        const int mt = w & 1;
        const int ch = w >> 1;
        floatx4 acc = (floatx4){0.f, 0.f, 0.f, 0.f};
        int r = base + mt * 16 + l16;  if (r >= M) r = M - 1;
        #pragma unroll
        for (int kt = 0; kt < 8; kt++) {
            const int koff = (kt & 3) * 32 + q * 8;
            short8 am = (kt < 4)
                ? *(const short8*)(hb_in + (long)r * DFEAT + koff)
                : *(const short8*)&mean_s[(mt * 16 + l16) * LDM + koff];
            long fb = ((long)(kt * NT + ch) * 64 + lane) * 8;
            short8 bhi = *(const short8*)(Whi + fb);
            short8 blo = *(const short8*)(Wlo + fb);
            acc = __builtin_amdgcn_mfma_f32_16x16x32_bf16(am, bhi, acc, 0, 0, 0);
            acc = __builtin_amdgcn_mfma_f32_16x16x32_bf16(am, blo, acc, 0, 0, 0);
        }
        float bv = bias[ch * 16 + l16];
        #pragma unroll
        for (int reg = 0; reg < 4; reg++) {
            int grow = base + mt * 16 + q * 4 + reg;
            if (grow < M) {
                float v = acc[reg] + bv;
                if (RELU) v = fmaxf(v, 0.f);
                long idx = (long)grow * N + ch * 16 + l16;
                if constexpr (FINAL) out[idx] = v;
                else                 hb_out[idx] = f2bf_rtne(v);
            }
        }
    } else {
        // NT == 4: 8 tiles; wave pairs (w, w+8) K-split self/mean, LDS reduce
        const int tid2 = w & 7;
        const int sel  = w >> 3;            // 0: self K-half, 1: mean K-half
        const int mt = tid2 & 1;
        const int ch = tid2 >> 1;
        floatx4 acc = (floatx4){0.f, 0.f, 0.f, 0.f};
        int r = base + mt * 16 + l16;  if (r >= M) r = M - 1;
        #pragma unroll
        for (int k = 0; k < 4; k++) {
            const int koff = k * 32 + q * 8;
            short8 am = sel
                ? *(const short8*)&mean_s[(mt * 16 + l16) * LDM + koff]
                : *(const short8*)(hb_in + (long)r * DFEAT + koff);
            int kt = sel ? k + 4 : k;
            long fb = ((long)(kt * NT + ch) * 64 + lane) * 8;
            short8 bhi = *(const short8*)(Whi + fb);
            short8 blo = *(const short8*)(Wlo + fb);
            acc = __builtin_amdgcn_mfma_f32_16x16x32_bf16(am, bhi, acc, 0, 0, 0);
            acc = __builtin_amdgcn_mfma_f32_16x16x32_bf16(am, blo, acc, 0, 0, 0);
        }
        if (sel) {
            #pragma unroll
            for (int reg = 0; reg < 4; reg++)
                red_s[(tid2 * 64 + lane) * 4 + reg] = acc[reg];
        }
        __syncthreads();
        if (!sel) {
            float bv = bias[ch * 16 + l16];
            #pragma unroll
            for (int reg = 0; reg < 4; reg++) {
                int grow = base + mt * 16 + q * 4 + reg;
                if (grow < M) {
                    float v = acc[reg] + red_s[(tid2 * 64 + lane) * 4 + reg] + bv;
                    if (RELU) v = fmaxf(v, 0.f);
                    long idx = (long)grow * N + ch * 16 + l16;
                    if constexpr (FINAL) out[idx] = v;
                    else                 hb_out[idx] = f2bf_rtne(v);
                }
            }
        }
    }
}

extern "C" void kernel_launch(void* const* d_in, const int* in_sizes, int n_in,
                              void* d_out, int out_size, void* d_ws, size_t ws_size,
                              hipStream_t stream) {
    const float* x   = (const float*)d_in[0];
    const int*   ei  = (const int*)d_in[1];
    const float* Ws0 = (const float*)d_in[2];
    const float* Wn0 = (const float*)d_in[3];
    const float* b0  = (const float*)d_in[4];
    const float* Ws1 = (const float*)d_in[5];
    const float* Wn1 = (const float*)d_in[6];
    const float* b1  = (const float*)d_in[7];
    const float* Ws2 = (const float*)d_in[8];
    const float* Wn2 = (const float*)d_in[9];
    const float* b2  = (const float*)d_in[10];
    float* out = (float*)d_out;

    const int* src = ei;
    const int* dst = ei + N_EDGES;

    // ---- workspace layout ----
    char* ws = (char*)d_ws;
    float* invdeg     = (float*)ws;   ws += 50176 * 4;
    int*   cnt        = (int*)ws;     ws += 50176 * 4;
    int*   row_ptr    = (int*)ws;     ws += 50432 * 4;
    int*   cursor     = (int*)ws;     ws += 50432 * 4;
    int*   bsum       = (int*)ws;     ws += 256 * 4;
    unsigned* ctrs    = (unsigned*)ws; ws += 256 * 4;
    unsigned short* sorted_src = (unsigned short*)ws; ws += 600064 * 2;
    unsigned short* Whi0 = (unsigned short*)ws; ws += 8 * 8 * 64 * 8 * 2;   // 64 KB
    unsigned short* Wlo0 = (unsigned short*)ws; ws += 8 * 8 * 64 * 8 * 2;
    unsigned short* Whi1 = (unsigned short*)ws; ws += 8 * 8 * 64 * 8 * 2;
    unsigned short* Wlo1 = (unsigned short*)ws; ws += 8 * 8 * 64 * 8 * 2;
    unsigned short* Whi2 = (unsigned short*)ws; ws += 8 * 4 * 64 * 8 * 2;   // 32 KB
    unsigned short* Wlo2 = (unsigned short*)ws; ws += 8 * 4 * 64 * 8 * 2;
    unsigned short* hb_a = (unsigned short*)ws; ws += (long)N_NODES * DFEAT * 2; // 12.8 MB
    unsigned short* hb_b = (unsigned short*)ws; ws += (long)N_NODES * DFEAT * 2; // 12.8 MB

    // ---- dispatch 1: prep ----
    sage_prep_kernel<<<1024, 256, 0, stream>>>(
        x, Ws0, Wn0, Ws1, Wn1, Ws2, Wn2,
        Whi0, Wlo0, Whi1, Wlo1, Whi2, Wlo2, hb_a, cnt, ctrs);

    // ---- dispatch 2: CSR build (hist+scan+fill, internal barriers) ----
    sage_csr_kernel<<<SCAN_NB, 256, 0, stream>>>(
        src, dst, cnt, bsum, row_ptr, cursor, invdeg, sorted_src, ctrs);

    const int layer_blocks = (N_NODES + 31) / 32;   // 1563

    // ---- dispatches 3-5: fused layers (hb ping-pong) ----
    sage_layer_kernel<8, true, false><<<layer_blocks, 1024, 0, stream>>>(
        hb_a, row_ptr, sorted_src, invdeg, Whi0, Wlo0, b0, nullptr, hb_b, N_NODES);
    sage_layer_kernel<8, true, false><<<layer_blocks, 1024, 0, stream>>>(
        hb_b, row_ptr, sorted_src, invdeg, Whi1, Wlo1, b1, nullptr, hb_a, N_NODES);
    sage_layer_kernel<4, false, true><<<layer_blocks, 1024, 0, stream>>>(
        hb_a, row_ptr, sorted_src, invdeg, Whi2, Wlo2, b2, out, nullptr, N_NODES);
}